// Round 3
// baseline (21408.667 us; speedup 1.0000x reference)
//
#include <hip/hip_runtime.h>
#include <hip/hip_bf16.h>

// B=64, T=512, D=H=1024, 2-layer masked LSTM. Persistent kernel, 128 WGs x 256 thr.
// v6: HALVED SYNC WIDTH. Each WG owns 16 h-columns (was 8) -> 64 WGs/layer.
// Rationale: LDS forces 1 WG/CU -> 1 wave/SIMD -> ~512 VGPR budget; v5 used only
// 216. Widening N/WG to 16 cols (bf[16][4]=256 VGPR) halves arrivals/step,
// pollers, and the straggler population (max over 64 not 128 WGs) while kmain
// grows only 128->256 MFMA (~0.5us, far below the sync chain). af ring 8->4 to
// keep live VGPRs ~410. Sync design unchanged from v5: flat 8-leaf epoch
// barriers (8 WGs/leaf, target 8*t), cached h loads + per-step agent-acquire
// (selective L2 inv, verified cheap in v5), sc-bypass h stores + vmcnt(0) drain,
// rnnout stores deferred past the arrive. Layer0 free-runs 3 ahead (h0 ring 4).

#define NTT 512

typedef __attribute__((ext_vector_type(8))) short short8;
typedef __attribute__((ext_vector_type(4))) float floatx4;
typedef __attribute__((ext_vector_type(4))) unsigned short ushort4v;
typedef unsigned long long ull;

#define LDS_TOTAL 90112  // force 1 WG/CU; first 48KB = reduction buf

#define AT_LD(p) __hip_atomic_load((p), __ATOMIC_RELAXED, __HIP_MEMORY_SCOPE_AGENT)
#define AT_ST(p, v) __hip_atomic_store((p), (v), __ATOMIC_RELAXED, __HIP_MEMORY_SCOPE_AGENT)
#define AT_ADD(p, v) __hip_atomic_fetch_add((p), (v), __ATOMIC_RELAXED, __HIP_MEMORY_SCOPE_AGENT)

__device__ __forceinline__ unsigned short f2bf(float f) {
  unsigned int u = __float_as_uint(f);
  u += 0x7fffu + ((u >> 16) & 1u);  // RNE
  return (unsigned short)(u >> 16);
}
__device__ __forceinline__ float sigmf(float x) { return 1.0f / (1.0f + __expf(-x)); }
__device__ __forceinline__ float tanhfa(float x) { return 1.0f - 2.0f / (1.0f + __expf(2.0f * x)); }

// ---- phase-0 flat full-grid barrier (128 WGs), WITH full fences
__device__ __forceinline__ void fullbar(ull* fb) {
  __syncthreads();
  if (threadIdx.x == 0) {
    __builtin_amdgcn_fence(__ATOMIC_RELEASE, "agent");
    AT_ADD(fb, 1ull);
    while (AT_LD(fb) < 128ull) __builtin_amdgcn_s_sleep(1);
    __builtin_amdgcn_fence(__ATOMIC_ACQUIRE, "agent");
  }
  __syncthreads();
}

// ---- flattened per-layer epoch barrier ----
// arrive: +1 on this WG's leaf, after all waves' h sc-stores acked at L3.
__device__ __forceinline__ void layer_arrive(ull* base, int sub) {
  asm volatile("s_waitcnt vmcnt(0)" ::: "memory");
  __syncthreads();
  if (threadIdx.x == 0) AT_ADD(base + 16 + 16 * (sub & 7), 1ull);
}

// min over the 8 leaf counters; 8 independent loads -> ~one L3 RTT per round
__device__ __forceinline__ ull leafmin(const ull* base) {
  ull v[8];
#pragma unroll
  for (int l = 0; l < 8; ++l) v[l] = AT_LD(base + 16 + 16 * l);
  ull m = v[0];
#pragma unroll
  for (int l = 1; l < 8; ++l) m = v[l] < m ? v[l] : m;
  return m;
}

// wait: all leaves of own >= 8*ot and of oth >= 8*xt (skip if <=0), then an
// agent-acquire fence (selective L2 invalidate) so cached h loads see fresh data.
__device__ __forceinline__ void wait2(const ull* own, long long ot, const ull* oth, long long xt) {
  if (threadIdx.x == 0) {
    if (ot > 0) {
      const ull tgt = 8ull * (ull)ot;
      while (leafmin(own) < tgt) __builtin_amdgcn_s_sleep(1);
    }
    if (xt > 0) {
      const ull tgt = 8ull * (ull)xt;
      while (leafmin(oth) < tgt) __builtin_amdgcn_s_sleep(1);
    }
    __builtin_amdgcn_fence(__ATOMIC_ACQUIRE, "agent");
  }
  __syncthreads();
}

// ---- A-fragment load: plain cached 16B load (h coherence via per-step acquire)
__device__ __forceinline__ short8 ldfrag(const char* p) { return *(const short8*)p; }

// fill af ring of 4 kt
__device__ __forceinline__ void ringfill(const char* const* aPm, short8 (*af)[4]) {
#pragma unroll
  for (int kt = 0; kt < 4; ++kt)
#pragma unroll
    for (int mt = 0; mt < 4; ++mt) af[kt][mt] = ldfrag(aPm[mt] + kt * 64);
}

__device__ __forceinline__ void kmain(const char* const* aPm, short8 (*af)[4],
                                      const short8 (*bfr)[4], floatx4 (*acc)[4]) {
#pragma unroll
  for (int kt = 0; kt < 16; ++kt) {
#pragma unroll
    for (int mt = 0; mt < 4; ++mt)
#pragma unroll
      for (int nt = 0; nt < 4; ++nt)
        acc[mt][nt] = __builtin_amdgcn_mfma_f32_16x16x32_bf16(
            af[kt & 3][mt], bfr[kt][nt], acc[mt][nt], 0, 0, 0);
    if (kt < 12) {
#pragma unroll
      for (int mt = 0; mt < 4; ++mt)
        af[kt & 3][mt] = ldfrag(aPm[mt] + (kt + 4) * 64);
    }
  }
}

__global__ __launch_bounds__(256, 1) void lstm2_persist(
    const float* __restrict__ xin, const int* __restrict__ lens,
    const float* __restrict__ W0, const float* __restrict__ U0, const float* __restrict__ b0v,
    const float* __restrict__ W1, const float* __restrict__ U1, const float* __restrict__ b1v,
    float* __restrict__ out, ull* __restrict__ ws) {
  extern __shared__ char smem[];
  float* red = (float*)smem;  // [12][4][64][4] f32 = 48KB

  ull* bar0 = ws;           // layer-0 epoch leaves @16+16l (128B apart)
  ull* bar1 = ws + 512;     // layer-1 epoch leaves
  ull* fbar = ws + 1024;    // phase-0 flat full barrier
  unsigned short* hbufs = (unsigned short*)(ws + 2048);  // byte 16384

  const int tid = threadIdx.x;
  const int bid = blockIdx.x;
  const int layer = bid >> 6;
  const int sub = bid & 63;
  const int hc0 = sub * 16;
  const int wave = tid >> 6;
  const int lane = tid & 63;
  const int c16 = lane & 15;
  const int rowgrp = lane >> 4;

  // h0 ring of 4 (layer0 may run ahead), h1 ping-pong of 2. 64x1024 bf16 each.
  unsigned short* h0r[4] = {hbufs, hbufs + 65536, hbufs + 131072, hbufs + 196608};
  unsigned short* h1r[2] = {hbufs + 262144, hbufs + 327680};

  // ---------------- phase 0 ----------------
  const unsigned int gid = (unsigned int)bid * 256u + (unsigned int)tid;
  for (unsigned int i = gid; i < 196608u; i += 32768u) ((unsigned int*)hbufs)[i] = 0u;
  {
    // x (B,T,D) fp32 -> bf16 aliased into d_out at (b*512+t)*4096 bytes.
    const floatx4* xs = (const floatx4*)xin;
    for (unsigned int q = gid; q < 8388608u; q += 32768u) {
      unsigned int d4 = q & 255u;
      unsigned int bt = q >> 8;
      floatx4 v = xs[q];
      ushort4v o;
      o.x = f2bf(v.x); o.y = f2bf(v.y); o.z = f2bf(v.z); o.w = f2bf(v.w);
      *((ushort4v*)((char*)out + (size_t)bt * 4096) + d4) = o;
    }
  }
  // B fragments -> VGPRs (wave w: K in [512w,512w+512); w<2 = W rows, w>=2 = U rows)
  // nt covers: block pair (nt&1: 0=i/f, 1=g/o; c16>>3 picks within pair) at
  // column-half ch = nt>>1 (8 cols each).
  const float* Wm = layer ? W1 : W0;
  const float* Um = layer ? U1 : U0;
  const float* Bsrc = (wave < 2) ? Wm : Um;
  const int kbase = (wave & 1) * 512;
  short8 bf[16][4];
#pragma unroll
  for (int kt = 0; kt < 16; ++kt)
#pragma unroll
    for (int nt = 0; nt < 4; ++nt) {
      const int zc = ((nt & 1) * 2 + (c16 >> 3)) * 1024 + hc0 + (nt >> 1) * 8 + (c16 & 7);
      const float* col = Bsrc + (size_t)(kbase + kt * 32 + rowgrp * 8) * 4096 + zc;
      short8 v;
#pragma unroll
      for (int j = 0; j < 8; ++j) v[j] = (short)f2bf(col[(size_t)j * 4096]);
      bf[kt][nt] = v;
    }
  const float* bv = layer ? b1v : b0v;
  float bias0[2], bias1[2];
#pragma unroll
  for (int ch = 0; ch < 2; ++ch) {
    bias0[ch] = bv[(c16 >> 3) * 1024 + hc0 + ch * 8 + (c16 & 7)];
    bias1[ch] = bv[(2 + (c16 >> 3)) * 1024 + hc0 + ch * 8 + (c16 & 7)];
  }
  int lens4[4];
#pragma unroll
  for (int r = 0; r < 4; ++r) lens4[r] = lens[wave * 16 + rowgrp * 4 + r];

  fullbar(fbar);

  // ---------------- recurrence ----------------
  float hst[2][4] = {{0.f, 0.f, 0.f, 0.f}, {0.f, 0.f, 0.f, 0.f}};
  float cst[2][4] = {{0.f, 0.f, 0.f, 0.f}, {0.f, 0.f, 0.f, 0.f}};

#pragma unroll 1
  for (int t = 0; t < NTT; ++t) {
    const char* aPm[4];
    short8 af[4][4];
    bool isX;  // this wave's A comes from x (prefetchable) vs h (post-wait only)
    {
      const char* base0;
      size_t pitch;
      if (layer == 0) {
        if (wave < 2) { base0 = (const char*)out + (size_t)t * 4096 + (size_t)wave * 1024;
                        pitch = (size_t)NTT * 4096; isX = true; }
        else          { base0 = (const char*)h0r[(t + 3) & 3] + (size_t)(wave - 2) * 1024;
                        pitch = 2048; isX = false; }
      } else {
        if (wave < 2) { base0 = (const char*)h0r[t & 3] + (size_t)wave * 1024; }
        else          { base0 = (const char*)h1r[(t + 1) & 1] + (size_t)(wave - 2) * 1024; }
        pitch = 2048; isX = false;
      }
      const char* aP = base0 + (size_t)c16 * pitch + (size_t)rowgrp * 16;
#pragma unroll
      for (int mt = 0; mt < 4; ++mt) aPm[mt] = aP + (size_t)mt * 16 * pitch;
    }

    if (isX) ringfill(aPm, af);  // x is static: prefetch before the wait

    if (layer == 0) wait2(bar0, t, bar1, (long long)t - 3);
    else            wait2(bar1, t, bar0, (long long)t + 1);

    floatx4 acc[4][4];
#pragma unroll
    for (int mt = 0; mt < 4; ++mt)
#pragma unroll
      for (int nt = 0; nt < 4; ++nt) { floatx4 z = {0.f, 0.f, 0.f, 0.f}; acc[mt][nt] = z; }

    if (isX) {
      kmain(aPm, af, bf, acc);
    } else {
      ringfill(aPm, af);
      kmain(aPm, af, bf, acc);
    }

    // cross-wave K reduction (wave keeps m-tile == wave)
#pragma unroll
    for (int mt = 0; mt < 4; ++mt)
      if (mt != wave) {
        int slot = mt * 3 + wave - (wave > mt ? 1 : 0);
#pragma unroll
        for (int nt = 0; nt < 4; ++nt)
          *(floatx4*)&red[((slot * 4 + nt) * 64 + lane) * 4] = acc[mt][nt];
      }
    __syncthreads();
    floatx4 z[4];
#pragma unroll
    for (int nt = 0; nt < 4; ++nt) z[nt] = acc[wave][nt];
#pragma unroll
    for (int q = 0; q < 3; ++q) {
      int slot = wave * 3 + q;
#pragma unroll
      for (int nt = 0; nt < 4; ++nt)
        z[nt] += *(const floatx4*)&red[((slot * 4 + nt) * 64 + lane) * 4];
    }
#pragma unroll
    for (int ch = 0; ch < 2; ++ch) {
      z[ch * 2 + 0] += bias0[ch];
      z[ch * 2 + 1] += bias1[ch];
    }

    unsigned short* hW = layer ? h1r[t & 1] : h0r[t & 3];
    float2 f2s[2][4];

#pragma unroll
    for (int ch = 0; ch < 2; ++ch) {
      const int col = hc0 + ch * 8 + c16;  // valid where c16 < 8
#pragma unroll
      for (int r = 0; r < 4; ++r) {
        float zi = z[ch * 2 + 0][r], zg = z[ch * 2 + 1][r];
        float zf = __shfl_xor(zi, 8);
        float zo = __shfl_xor(zg, 8);
        float h2, hu_f = 0.f;
        unsigned short hu = 0;
        if (c16 < 8) {
          float ig = sigmf(zi), fg = sigmf(zf), gg = tanhfa(zg), og = sigmf(zo);
          float cn = fg * cst[ch][r] + ig * gg;
          float hn = og * tanhfa(cn);
          bool m = t < lens4[r];
          h2 = m ? hn : hst[ch][r];
          float c2 = m ? cn : cst[ch][r];
          hst[ch][r] = h2;
          cst[ch][r] = c2;
          hu = f2bf(h2);
          hu_f = h2;
        }
        // pair adjacent cols -> one u32 coherent (L2-bypass) store
        unsigned int up = __shfl_xor((unsigned int)hu, 1);
        float hp = __shfl_xor(hu_f, 1);
        if (c16 < 8 && !(c16 & 1)) {
          int b = wave * 16 + rowgrp * 4 + r;
          unsigned int w = (unsigned int)hu | (up << 16);
          AT_ST((unsigned int*)(hW + b * 1024 + col), w);
          f2s[ch][r] = make_float2(hu_f, hp);
        }
      }
    }

    if (layer == 0) layer_arrive(bar0, sub);
    else            layer_arrive(bar1, sub);

    // rnnout f32 stores AFTER the arrive: off the vmcnt(0) drain path;
    // they complete during the next step's wait.
    if (layer && c16 < 8 && !(c16 & 1)) {
#pragma unroll
      for (int ch = 0; ch < 2; ++ch) {
        const int col = hc0 + ch * 8 + c16;
#pragma unroll
        for (int r = 0; r < 4; ++r) {
          int b = wave * 16 + rowgrp * 4 + r;
          *(float2*)&out[((size_t)b * 512 + (size_t)t) * 1024 + col] = f2s[ch][r];
        }
      }
    }
  }

  if (layer && c16 < 8) {
#pragma unroll
    for (int ch = 0; ch < 2; ++ch) {
      const int col = hc0 + ch * 8 + c16;
#pragma unroll
      for (int r = 0; r < 4; ++r) {
        int b = wave * 16 + rowgrp * 4 + r;
        out[(size_t)33554432 + (size_t)b * 1024 + col] = hst[ch][r];
        out[(size_t)33554432 + 65536 + (size_t)b * 1024 + col] = cst[ch][r];
      }
    }
  }
}

extern "C" void kernel_launch(void* const* d_in, const int* in_sizes, int n_in,
                              void* d_out, int out_size, void* d_ws, size_t ws_size,
                              hipStream_t stream) {
  (void)in_sizes; (void)n_in; (void)out_size; (void)ws_size;
  const float* x  = (const float*)d_in[0];
  const int* lens = (const int*)d_in[1];
  const float* W0 = (const float*)d_in[2];
  const float* U0 = (const float*)d_in[3];
  const float* b0 = (const float*)d_in[4];
  const float* W1 = (const float*)d_in[5];
  const float* U1 = (const float*)d_in[6];
  const float* b1 = (const float*)d_in[7];

  (void)hipFuncSetAttribute((const void*)lstm2_persist,
                            hipFuncAttributeMaxDynamicSharedMemorySize, LDS_TOTAL);
  hipMemsetAsync(d_ws, 0, 16384, stream);  // bar0/bar1/fbar

  lstm2_persist<<<dim3(128), dim3(256), LDS_TOTAL, stream>>>(
      x, lens, W0, U0, b0, W1, U1, b1, (float*)d_out, (ull*)d_ws);
}

// Round 4
// 10229.248 us; speedup vs baseline: 2.0929x; 2.0929x over previous
//
#include <hip/hip_runtime.h>
#include <hip/hip_bf16.h>

// B=64, T=512, D=H=1024, 2-layer masked LSTM. Persistent kernel, 256 WGs x 256 thr.
// v7 (v5 shape: 8 cols/WG, 128 WGs/layer — register-safe; v4/v6 proved wider
// tiles spill). Sync redesign:
// (a) NO RMW barriers: each WG publishes a per-WG epoch word (pure AT_ST into
//     one of 128 u32 flags/layer, 16 per 64B line). No fetch_add serialization.
// (b) CHUNKED consumption: flags grouped so leaf g = h columns [128g,128g+128)
//     = 4 MFMA k-steps. A U-wave gathers its 64 flags (one per-lane load +
//     __ballot), then per chunk: wait-ready -> issue coherent loads -> MFMA the
//     PREVIOUS chunk. Straggler tail overlaps load latency + 3/4 of the GEMM.
// (c) h loads are L2-bypass atomic loads (v3-proven) -> no acquire fences at
//     all in the loop. x stays cached/L2; weights stay in VGPRs.
// (d) layer0 x-waves have no wait; ring-overwrite safety via a slack-3 guard
//     polled by layer0 U-waves (flags1 >= t-3) before their chunk loop; all
//     h-stores sit behind the intra-WG reduce barrier, so the guard covers the
//     whole WG. Layer1's ping-pong guard is implied by its own chunk-waits.
// Layer0 free-runs up to 3 steps ahead (h0 ring of 4); layer1 needs epoch0>=t+1.

#define NTT 512

typedef __attribute__((ext_vector_type(8))) short short8;
typedef __attribute__((ext_vector_type(4))) float floatx4;
typedef __attribute__((ext_vector_type(4))) unsigned short ushort4v;
typedef unsigned long long ull;

#define LDS_TOTAL 90112  // force 1 WG/CU; first 24KB = reduction buf

#define AT_LD(p) __hip_atomic_load((p), __ATOMIC_RELAXED, __HIP_MEMORY_SCOPE_AGENT)
#define AT_ST(p, v) __hip_atomic_store((p), (v), __ATOMIC_RELAXED, __HIP_MEMORY_SCOPE_AGENT)
#define AT_ADD(p, v) __hip_atomic_fetch_add((p), (v), __ATOMIC_RELAXED, __HIP_MEMORY_SCOPE_AGENT)

__device__ __forceinline__ unsigned short f2bf(float f) {
  unsigned int u = __float_as_uint(f);
  u += 0x7fffu + ((u >> 16) & 1u);  // RNE
  return (unsigned short)(u >> 16);
}
__device__ __forceinline__ float sigmf(float x) { return 1.0f / (1.0f + __expf(-x)); }
__device__ __forceinline__ float tanhfa(float x) { return 1.0f - 2.0f / (1.0f + __expf(2.0f * x)); }

// ---- phase-0 flat full-grid barrier (256 WGs), WITH full fences
__device__ __forceinline__ void fullbar(ull* fb) {
  __syncthreads();
  if (threadIdx.x == 0) {
    __builtin_amdgcn_fence(__ATOMIC_RELEASE, "agent");
    AT_ADD(fb, 1ull);
    while (AT_LD(fb) < 256ull) __builtin_amdgcn_s_sleep(1);
    __builtin_amdgcn_fence(__ATOMIC_ACQUIRE, "agent");
  }
  __syncthreads();
}

// ---- A-fragment loads ----
// cached 16B load (x path: immutable data)
__device__ __forceinline__ short8 ldfrag(const char* p) { return *(const short8*)p; }
// L2-bypassing coherent load (h path: mutable, producer stores are sc-bypass)
__device__ __forceinline__ short8 ldcoh(const char* p) {
  union { short8 s; ull q[2]; } u;
  u.q[0] = AT_LD((const ull*)p);
  u.q[1] = AT_LD((const ull*)(p + 8));
  return u.s;
}

// x path: fill ring of 8 kt (cached)
__device__ __forceinline__ void ringfill(const char* const* aPm, short8 (*af)[4]) {
#pragma unroll
  for (int kt = 0; kt < 8; ++kt)
#pragma unroll
    for (int mt = 0; mt < 4; ++mt) af[kt][mt] = ldfrag(aPm[mt] + kt * 64);
}

// x path: full K=512 GEMM with cached ring refill
__device__ __forceinline__ void kmain(const char* const* aPm, short8 (*af)[4],
                                      const short8 (*bfr)[2], floatx4 (*acc)[2]) {
#pragma unroll
  for (int kt = 0; kt < 16; ++kt) {
#pragma unroll
    for (int mt = 0; mt < 4; ++mt)
#pragma unroll
      for (int nt = 0; nt < 2; ++nt)
        acc[mt][nt] = __builtin_amdgcn_mfma_f32_16x16x32_bf16(
            af[kt & 7][mt], bfr[kt][nt], acc[mt][nt], 0, 0, 0);
    if (kt < 8) {
#pragma unroll
      for (int mt = 0; mt < 4; ++mt)
        af[kt & 7][mt] = ldfrag(aPm[mt] + (kt + 8) * 64);
    }
  }
}

// h path: load one chunk (4 kt x 4 mt) with coherent loads
__device__ __forceinline__ void ringchunk(const char* const* aPm, short8 (*afc)[4], int kb) {
#pragma unroll
  for (int j = 0; j < 4; ++j)
#pragma unroll
    for (int mt = 0; mt < 4; ++mt) afc[j][mt] = ldcoh(aPm[mt] + (kb + j) * 64);
}

// h path: MFMA one chunk
__device__ __forceinline__ void kchunk(const short8 (*afc)[4], const short8 (*bfr)[2],
                                       floatx4 (*acc)[2], int kb) {
#pragma unroll
  for (int j = 0; j < 4; ++j)
#pragma unroll
    for (int mt = 0; mt < 4; ++mt)
#pragma unroll
      for (int nt = 0; nt < 2; ++nt)
        acc[mt][nt] = __builtin_amdgcn_mfma_f32_16x16x32_bf16(
            afc[j][mt], bfr[kb + j][nt], acc[mt][nt], 0, 0, 0);
}

__global__ __launch_bounds__(256, 1) void lstm2_persist(
    const float* __restrict__ xin, const int* __restrict__ lens,
    const float* __restrict__ W0, const float* __restrict__ U0, const float* __restrict__ b0v,
    const float* __restrict__ W1, const float* __restrict__ U1, const float* __restrict__ b1v,
    float* __restrict__ out, ull* __restrict__ ws) {
  extern __shared__ char smem[];
  float* red = (float*)smem;  // [12][2][64][4] f32 = 24KB

  // ws layout: flags0 @byte128 (128 u32), flags1 @byte640 (128 u32),
  // fbar @byte8192, hbufs @byte16384.
  unsigned* flags0 = (unsigned*)(ws + 16);
  unsigned* flags1 = (unsigned*)(ws + 80);
  ull* fbar = ws + 1024;
  unsigned short* hbufs = (unsigned short*)(ws + 2048);

  const int tid = threadIdx.x;
  const int bid = blockIdx.x;
  const int layer = bid >> 7;
  const int sub = bid & 127;
  const int hc0 = sub * 8;
  const int wave = tid >> 6;
  const int lane = tid & 63;
  const int c16 = lane & 15;
  const int rowgrp = lane >> 4;
  unsigned* flagsL = layer ? flags1 : flags0;

  // h0 ring of 4 (layer0 may run ahead), h1 ping-pong of 2. 64x1024 bf16 each.
  unsigned short* h0r[4] = {hbufs, hbufs + 65536, hbufs + 131072, hbufs + 196608};
  unsigned short* h1r[2] = {hbufs + 262144, hbufs + 327680};

  // ---------------- phase 0 ----------------
  const unsigned int gid = (unsigned int)bid * 256u + (unsigned int)tid;
  for (unsigned int i = gid; i < 196608u; i += 65536u) ((unsigned int*)hbufs)[i] = 0u;
  {
    // x (B,T,D) fp32 -> bf16 aliased into d_out at (b*512+t)*4096 bytes.
    const floatx4* xs = (const floatx4*)xin;
    for (unsigned int q = gid; q < 8388608u; q += 65536u) {
      unsigned int d4 = q & 255u;
      unsigned int bt = q >> 8;
      floatx4 v = xs[q];
      ushort4v o;
      o.x = f2bf(v.x); o.y = f2bf(v.y); o.z = f2bf(v.z); o.w = f2bf(v.w);
      *((ushort4v*)((char*)out + (size_t)bt * 4096) + d4) = o;
    }
  }
  // B fragments -> VGPRs (wave w: K in [512w,512w+512); w<2 = W rows, w>=2 = U rows)
  const float* Wm = layer ? W1 : W0;
  const float* Um = layer ? U1 : U0;
  const float* Bsrc = (wave < 2) ? Wm : Um;
  const int kbase = (wave & 1) * 512;
  short8 bf[16][2];
#pragma unroll
  for (int kt = 0; kt < 16; ++kt)
#pragma unroll
    for (int nt = 0; nt < 2; ++nt) {
      const int zc = (nt * 2 + (c16 >> 3)) * 1024 + hc0 + (c16 & 7);
      const float* col = Bsrc + (size_t)(kbase + kt * 32 + rowgrp * 8) * 4096 + zc;
      short8 v;
#pragma unroll
      for (int j = 0; j < 8; ++j) v[j] = (short)f2bf(col[(size_t)j * 4096]);
      bf[kt][nt] = v;
    }
  const float* bv = layer ? b1v : b0v;
  const float bias0 = bv[(c16 >> 3) * 1024 + hc0 + (c16 & 7)];
  const float bias1 = bv[(2 + (c16 >> 3)) * 1024 + hc0 + (c16 & 7)];
  int lens4[4];
#pragma unroll
  for (int r = 0; r < 4; ++r) lens4[r] = lens[wave * 16 + rowgrp * 4 + r];

  fullbar(fbar);

  // ---------------- recurrence ----------------
  float hst[4] = {0.f, 0.f, 0.f, 0.f};
  float cst[4] = {0.f, 0.f, 0.f, 0.f};
  const int col = hc0 + c16;

#pragma unroll 1
  for (int t = 0; t < NTT; ++t) {
    const char* aPm[4];
    short8 af[8][4];
    bool isX;
    {
      const char* base0;
      size_t pitch;
      if (layer == 0) {
        if (wave < 2) { base0 = (const char*)out + (size_t)t * 4096 + (size_t)wave * 1024;
                        pitch = (size_t)NTT * 4096; isX = true; }
        else          { base0 = (const char*)h0r[(t + 3) & 3] + (size_t)(wave - 2) * 1024;
                        pitch = 2048; isX = false; }
      } else {
        if (wave < 2) { base0 = (const char*)h0r[t & 3] + (size_t)wave * 1024; }
        else          { base0 = (const char*)h1r[(t + 1) & 1] + (size_t)(wave - 2) * 1024; }
        pitch = 2048; isX = false;
      }
      const char* aP = base0 + (size_t)c16 * pitch + (size_t)rowgrp * 16;
#pragma unroll
      for (int mt = 0; mt < 4; ++mt) aPm[mt] = aP + (size_t)mt * 16 * pitch;
    }

    floatx4 acc[4][2];
#pragma unroll
    for (int mt = 0; mt < 4; ++mt)
#pragma unroll
      for (int nt = 0; nt < 2; ++nt) { floatx4 z = {0.f, 0.f, 0.f, 0.f}; acc[mt][nt] = z; }

    if (isX) {
      // layer0 x-waves: immutable input, no wait at all.
      ringfill(aPm, af);
      kmain(aPm, af, bf, acc);
    } else {
      // ring-overwrite guard (layer0 U-waves only): all layer1 WGs must have
      // finished step t-4 (flags1 >= t-3) before this WG may store h0r[t&3].
      // h-stores sit behind the reduce barrier, so this covers the whole WG.
      if (layer == 0 && t >= 4) {
        const unsigned g4 = (unsigned)(t - 3);
        while (true) {
          bool ok = (AT_LD(flags1 + lane) >= g4) && (AT_LD(flags1 + 64 + lane) >= g4);
          if (__all(ok)) break;
          __builtin_amdgcn_s_sleep(2);
        }
      }
      // chunked consumption: producer flags for this wave's K-half.
      const unsigned* fl;     // producer layer's flags
      int half;               // which K-half (0: cols 0..511, 1: cols 512..1023)
      unsigned tgt;           // required epoch
      if (layer == 0)      { fl = flags0; half = wave - 2; tgt = (unsigned)t; }
      else if (wave < 2)   { fl = flags0; half = wave;     tgt = (unsigned)(t + 1); }
      else                 { fl = flags1; half = wave - 2; tgt = (unsigned)t; }
      const unsigned* fb = fl + half * 64;

      ull rdy = __ballot(AT_LD(fb + lane) >= tgt);
#pragma unroll
      for (int g = 0; g < 4; ++g) {
        const ull need = 0xFFFFull << (16 * g);
        while ((rdy & need) != need) {
          __builtin_amdgcn_s_sleep(1);
          rdy = __ballot(AT_LD(fb + lane) >= tgt);
        }
        ringchunk(aPm, &af[(g & 1) * 4], g * 4);
        if (g) kchunk(&af[((g - 1) & 1) * 4], bf, acc, (g - 1) * 4);
      }
      kchunk(&af[4], bf, acc, 12);
    }

    // cross-wave K reduction (wave keeps m-tile == wave)
#pragma unroll
    for (int mt = 0; mt < 4; ++mt)
      if (mt != wave) {
        int slot = mt * 3 + wave - (wave > mt ? 1 : 0);
        *(floatx4*)&red[((slot * 2 + 0) * 64 + lane) * 4] = acc[mt][0];
        *(floatx4*)&red[((slot * 2 + 1) * 64 + lane) * 4] = acc[mt][1];
      }
    __syncthreads();
    floatx4 z0 = acc[wave][0], z1 = acc[wave][1];
#pragma unroll
    for (int q = 0; q < 3; ++q) {
      int slot = wave * 3 + q;
      z0 += *(const floatx4*)&red[((slot * 2 + 0) * 64 + lane) * 4];
      z1 += *(const floatx4*)&red[((slot * 2 + 1) * 64 + lane) * 4];
    }
    z0 += bias0;
    z1 += bias1;

    unsigned short* hW = layer ? h1r[t & 1] : h0r[t & 3];
    float2 f2s[4];

#pragma unroll
    for (int r = 0; r < 4; ++r) {
      float zi = z0[r], zg = z1[r];
      float zf = __shfl_xor(zi, 8);
      float zo = __shfl_xor(zg, 8);
      float h2, hu_f = 0.f;
      unsigned short hu = 0;
      if (c16 < 8) {
        float ig = sigmf(zi), fg = sigmf(zf), gg = tanhfa(zg), og = sigmf(zo);
        float cn = fg * cst[r] + ig * gg;
        float hn = og * tanhfa(cn);
        bool m = t < lens4[r];
        h2 = m ? hn : hst[r];
        float c2 = m ? cn : cst[r];
        hst[r] = h2;
        cst[r] = c2;
        hu = f2bf(h2);
        hu_f = h2;
      }
      // pair adjacent cols -> one u32 coherent (L2-bypass) store
      unsigned int up = __shfl_xor((unsigned int)hu, 1);
      float hp = __shfl_xor(hu_f, 1);
      if (c16 < 8 && !(c16 & 1)) {
        int b = wave * 16 + rowgrp * 4 + r;
        unsigned int w = (unsigned int)hu | (up << 16);
        AT_ST((unsigned int*)(hW + b * 1024 + col), w);
        f2s[r] = make_float2(hu_f, hp);
      }
    }

    // publish: drain h sc-stores, then per-WG epoch word (pure store, no RMW)
    asm volatile("s_waitcnt vmcnt(0)" ::: "memory");
    __syncthreads();
    if (tid == 0) AT_ST(flagsL + sub, (unsigned)(t + 1));

    // rnnout f32 stores AFTER the publish: off the drain path.
    if (layer && c16 < 8 && !(c16 & 1)) {
#pragma unroll
      for (int r = 0; r < 4; ++r) {
        int b = wave * 16 + rowgrp * 4 + r;
        *(float2*)&out[((size_t)b * 512 + (size_t)t) * 1024 + col] = f2s[r];
      }
    }
  }

  if (layer && c16 < 8) {
#pragma unroll
    for (int r = 0; r < 4; ++r) {
      int b = wave * 16 + rowgrp * 4 + r;
      out[(size_t)33554432 + (size_t)b * 1024 + col] = hst[r];
      out[(size_t)33554432 + 65536 + (size_t)b * 1024 + col] = cst[r];
    }
  }
}

extern "C" void kernel_launch(void* const* d_in, const int* in_sizes, int n_in,
                              void* d_out, int out_size, void* d_ws, size_t ws_size,
                              hipStream_t stream) {
  (void)in_sizes; (void)n_in; (void)out_size; (void)ws_size;
  const float* x  = (const float*)d_in[0];
  const int* lens = (const int*)d_in[1];
  const float* W0 = (const float*)d_in[2];
  const float* U0 = (const float*)d_in[3];
  const float* b0 = (const float*)d_in[4];
  const float* W1 = (const float*)d_in[5];
  const float* U1 = (const float*)d_in[6];
  const float* b1 = (const float*)d_in[7];

  (void)hipFuncSetAttribute((const void*)lstm2_persist,
                            hipFuncAttributeMaxDynamicSharedMemorySize, LDS_TOTAL);
  hipMemsetAsync(d_ws, 0, 16384, stream);  // flags0/flags1/fbar

  lstm2_persist<<<dim3(256), dim3(256), LDS_TOTAL, stream>>>(
      x, lens, W0, U0, b0, W1, U1, b1, (float*)d_out, (ull*)d_ws);
}

// Round 5
// 8746.549 us; speedup vs baseline: 2.4477x; 1.1695x over previous
//
#include <hip/hip_runtime.h>
#include <hip/hip_bf16.h>

// B=64, T=512, D=H=1024, 2-layer masked LSTM. Persistent kernel, 256 WGs x 256 thr.
// v8 = v7 sync skeleton (per-WG store-flags, no RMW, ballot waits, layer0 ring-4
// free-run + slack-3 guard) with a BLOCKED h layout [128 kb][64 b][8 cols] bf16:
// - producer WG sub writes block kb=sub as ONE contiguous 1KB chunk: h staged in
//   LDS, wave0 stores it with 2 coalesced 8B-atomic insts + vmcnt(0) + flag.
//   (was: 256 scattered 4B lane-stores touching 64 lines at 16B each)
// - consumer A-fragment (mt,kt) = 16 contiguous bytes at kb*1024+row*16; wave
//   reads are full-line transactions. (was: 16B-granule reads strided 2KB)
// Same bytes, ~8-16x fewer L3 coherent transactions both directions — attacking
// the one cost shared by v3/v5/v7 (all ~19-21us/step across 3 sync designs).
// x path unchanged (cached row-major xz alias in d_out, prefetched pre-wait).
// Chunked consumption dropped (measured null in v7).

#define NTT 512

typedef __attribute__((ext_vector_type(8))) short short8;
typedef __attribute__((ext_vector_type(4))) float floatx4;
typedef __attribute__((ext_vector_type(4))) unsigned short ushort4v;
typedef unsigned long long ull;

#define LDS_TOTAL 90112  // force 1 WG/CU; 24KB red + 1KB hstage

#define AT_LD(p) __hip_atomic_load((p), __ATOMIC_RELAXED, __HIP_MEMORY_SCOPE_AGENT)
#define AT_ST(p, v) __hip_atomic_store((p), (v), __ATOMIC_RELAXED, __HIP_MEMORY_SCOPE_AGENT)
#define AT_ADD(p, v) __hip_atomic_fetch_add((p), (v), __ATOMIC_RELAXED, __HIP_MEMORY_SCOPE_AGENT)

__device__ __forceinline__ unsigned short f2bf(float f) {
  unsigned int u = __float_as_uint(f);
  u += 0x7fffu + ((u >> 16) & 1u);  // RNE
  return (unsigned short)(u >> 16);
}
__device__ __forceinline__ float sigmf(float x) { return 1.0f / (1.0f + __expf(-x)); }
__device__ __forceinline__ float tanhfa(float x) { return 1.0f - 2.0f / (1.0f + __expf(2.0f * x)); }

// ---- phase-0 flat full-grid barrier (256 WGs), WITH full fences
__device__ __forceinline__ void fullbar(ull* fb) {
  __syncthreads();
  if (threadIdx.x == 0) {
    __builtin_amdgcn_fence(__ATOMIC_RELEASE, "agent");
    AT_ADD(fb, 1ull);
    while (AT_LD(fb) < 256ull) __builtin_amdgcn_s_sleep(1);
    __builtin_amdgcn_fence(__ATOMIC_ACQUIRE, "agent");
  }
  __syncthreads();
}

// ---- A-fragment loads ----
// cached 16B load (x path: immutable data)
__device__ __forceinline__ short8 ldfrag(const char* p) { return *(const short8*)p; }
// L2-bypassing coherent load (h path: mutable, producer stores are sc-bypass)
__device__ __forceinline__ short8 ldcoh(const char* p) {
  union { short8 s; ull q[2]; } u;
  u.q[0] = AT_LD((const ull*)p);
  u.q[1] = AT_LD((const ull*)(p + 8));
  return u.s;
}

// x path: fill ring of 8 kt (cached, row-major xz: kt stride 64B)
__device__ __forceinline__ void ringfillX(const char* const* aPm, short8 (*af)[4]) {
#pragma unroll
  for (int kt = 0; kt < 8; ++kt)
#pragma unroll
    for (int mt = 0; mt < 4; ++mt) af[kt][mt] = ldfrag(aPm[mt] + kt * 64);
}
__device__ __forceinline__ void kmainX(const char* const* aPm, short8 (*af)[4],
                                       const short8 (*bfr)[2], floatx4 (*acc)[2]) {
#pragma unroll
  for (int kt = 0; kt < 16; ++kt) {
#pragma unroll
    for (int mt = 0; mt < 4; ++mt)
#pragma unroll
      for (int nt = 0; nt < 2; ++nt)
        acc[mt][nt] = __builtin_amdgcn_mfma_f32_16x16x32_bf16(
            af[kt & 7][mt], bfr[kt][nt], acc[mt][nt], 0, 0, 0);
    if (kt < 8) {
#pragma unroll
      for (int mt = 0; mt < 4; ++mt)
        af[kt & 7][mt] = ldfrag(aPm[mt] + (kt + 8) * 64);
    }
  }
}

// h path: blocked layout, kt advances kb by 4 -> stride 4096B
__device__ __forceinline__ void ringfillH(const char* const* aPm, short8 (*af)[4]) {
#pragma unroll
  for (int kt = 0; kt < 8; ++kt)
#pragma unroll
    for (int mt = 0; mt < 4; ++mt) af[kt][mt] = ldcoh(aPm[mt] + kt * 4096);
}
__device__ __forceinline__ void kmainH(const char* const* aPm, short8 (*af)[4],
                                       const short8 (*bfr)[2], floatx4 (*acc)[2]) {
#pragma unroll
  for (int kt = 0; kt < 16; ++kt) {
#pragma unroll
    for (int mt = 0; mt < 4; ++mt)
#pragma unroll
      for (int nt = 0; nt < 2; ++nt)
        acc[mt][nt] = __builtin_amdgcn_mfma_f32_16x16x32_bf16(
            af[kt & 7][mt], bfr[kt][nt], acc[mt][nt], 0, 0, 0);
    if (kt < 8) {
#pragma unroll
      for (int mt = 0; mt < 4; ++mt)
        af[kt & 7][mt] = ldcoh(aPm[mt] + (kt + 8) * 4096);
    }
  }
}

__global__ __launch_bounds__(256, 1) void lstm2_persist(
    const float* __restrict__ xin, const int* __restrict__ lens,
    const float* __restrict__ W0, const float* __restrict__ U0, const float* __restrict__ b0v,
    const float* __restrict__ W1, const float* __restrict__ U1, const float* __restrict__ b1v,
    float* __restrict__ out, ull* __restrict__ ws) {
  extern __shared__ char smem[];
  float* red = (float*)smem;  // [12][2][64][4] f32 = 24KB
  unsigned short* hstage = (unsigned short*)(smem + 24576);  // [64 b][8 col] = 1KB

  // ws layout: flags0 @byte128 (128 u32), flags1 @byte640 (128 u32),
  // fbar @byte8192, hbufs @byte16384.
  unsigned* flags0 = (unsigned*)(ws + 16);
  unsigned* flags1 = (unsigned*)(ws + 80);
  ull* fbar = ws + 1024;
  unsigned short* hbufs = (unsigned short*)(ws + 2048);

  const int tid = threadIdx.x;
  const int bid = blockIdx.x;
  const int layer = bid >> 7;
  const int sub = bid & 127;
  const int hc0 = sub * 8;
  const int wave = tid >> 6;
  const int lane = tid & 63;
  const int c16 = lane & 15;
  const int rowgrp = lane >> 4;
  unsigned* flagsL = layer ? flags1 : flags0;

  // h0 ring of 4 (layer0 may run ahead), h1 ping-pong of 2.
  // Each buffer: 128 blocks x 64 b x 8 cols bf16 = 128KB (blocked layout).
  unsigned short* h0r[4] = {hbufs, hbufs + 65536, hbufs + 131072, hbufs + 196608};
  unsigned short* h1r[2] = {hbufs + 262144, hbufs + 327680};

  // ---------------- phase 0 ----------------
  const unsigned int gid = (unsigned int)bid * 256u + (unsigned int)tid;
  for (unsigned int i = gid; i < 196608u; i += 65536u) ((unsigned int*)hbufs)[i] = 0u;
  {
    // x (B,T,D) fp32 -> bf16 aliased into d_out at (b*512+t)*4096 bytes.
    const floatx4* xs = (const floatx4*)xin;
    for (unsigned int q = gid; q < 8388608u; q += 65536u) {
      unsigned int d4 = q & 255u;
      unsigned int bt = q >> 8;
      floatx4 v = xs[q];
      ushort4v o;
      o.x = f2bf(v.x); o.y = f2bf(v.y); o.z = f2bf(v.z); o.w = f2bf(v.w);
      *((ushort4v*)((char*)out + (size_t)bt * 4096) + d4) = o;
    }
  }
  // B fragments -> VGPRs (wave w: K in [512w,512w+512); w<2 = W rows, w>=2 = U rows)
  const float* Wm = layer ? W1 : W0;
  const float* Um = layer ? U1 : U0;
  const float* Bsrc = (wave < 2) ? Wm : Um;
  const int kbase = (wave & 1) * 512;
  short8 bf[16][2];
#pragma unroll
  for (int kt = 0; kt < 16; ++kt)
#pragma unroll
    for (int nt = 0; nt < 2; ++nt) {
      const int zc = (nt * 2 + (c16 >> 3)) * 1024 + hc0 + (c16 & 7);
      const float* col = Bsrc + (size_t)(kbase + kt * 32 + rowgrp * 8) * 4096 + zc;
      short8 v;
#pragma unroll
      for (int j = 0; j < 8; ++j) v[j] = (short)f2bf(col[(size_t)j * 4096]);
      bf[kt][nt] = v;
    }
  const float* bv = layer ? b1v : b0v;
  const float bias0 = bv[(c16 >> 3) * 1024 + hc0 + (c16 & 7)];
  const float bias1 = bv[(2 + (c16 >> 3)) * 1024 + hc0 + (c16 & 7)];
  int lens4[4];
#pragma unroll
  for (int r = 0; r < 4; ++r) lens4[r] = lens[wave * 16 + rowgrp * 4 + r];

  fullbar(fbar);

  // ---------------- recurrence ----------------
  float hst[4] = {0.f, 0.f, 0.f, 0.f};
  float cst[4] = {0.f, 0.f, 0.f, 0.f};
  const int col = hc0 + c16;

#pragma unroll 1
  for (int t = 0; t < NTT; ++t) {
    const char* aPm[4];
    short8 af[8][4];
    floatx4 acc[4][2];
#pragma unroll
    for (int mt = 0; mt < 4; ++mt)
#pragma unroll
      for (int nt = 0; nt < 2; ++nt) { floatx4 z = {0.f, 0.f, 0.f, 0.f}; acc[mt][nt] = z; }

    if (layer == 0 && wave < 2) {
      // x path: immutable, cached, no wait at all.
      const char* base0 = (const char*)out + (size_t)t * 4096 + (size_t)wave * 1024;
      const size_t pitch = (size_t)NTT * 4096;
      const char* aP = base0 + (size_t)c16 * pitch + (size_t)rowgrp * 16;
#pragma unroll
      for (int mt = 0; mt < 4; ++mt) aPm[mt] = aP + (size_t)mt * 16 * pitch;
      ringfillX(aPm, af);
      kmainX(aPm, af, bf, acc);
    } else {
      // h path: blocked layout.
      const char* hb;
      int khalf;
      const unsigned* fl;
      unsigned tgt;
      if (layer == 0)    { hb = (const char*)h0r[(t + 3) & 3]; khalf = wave - 2; fl = flags0; tgt = (unsigned)t; }
      else if (wave < 2) { hb = (const char*)h0r[t & 3];       khalf = wave;     fl = flags0; tgt = (unsigned)(t + 1); }
      else               { hb = (const char*)h1r[(t + 1) & 1]; khalf = wave - 2; fl = flags1; tgt = (unsigned)t; }
#pragma unroll
      for (int mt = 0; mt < 4; ++mt)
        aPm[mt] = hb + (size_t)khalf * 65536 + (size_t)rowgrp * 1024 + (size_t)(mt * 16 + c16) * 16;

      // ring-overwrite guard (layer0 U-waves): all layer1 WGs past step t-4.
      if (layer == 0 && t >= 4) {
        const unsigned g4 = (unsigned)(t - 3);
        while (true) {
          bool ok = (AT_LD(flags1 + lane) >= g4) && (AT_LD(flags1 + 64 + lane) >= g4);
          if (__all(ok)) break;
          __builtin_amdgcn_s_sleep(2);
        }
      }
      // wait for all 64 producers of this K-half (one ballot gather per round)
      const unsigned* fb = fl + khalf * 64;
      while (!__all(AT_LD(fb + lane) >= tgt)) __builtin_amdgcn_s_sleep(1);

      ringfillH(aPm, af);
      kmainH(aPm, af, bf, acc);
    }

    // cross-wave K reduction (wave keeps m-tile == wave)
#pragma unroll
    for (int mt = 0; mt < 4; ++mt)
      if (mt != wave) {
        int slot = mt * 3 + wave - (wave > mt ? 1 : 0);
        *(floatx4*)&red[((slot * 2 + 0) * 64 + lane) * 4] = acc[mt][0];
        *(floatx4*)&red[((slot * 2 + 1) * 64 + lane) * 4] = acc[mt][1];
      }
    __syncthreads();
    floatx4 z0 = acc[wave][0], z1 = acc[wave][1];
#pragma unroll
    for (int q = 0; q < 3; ++q) {
      int slot = wave * 3 + q;
      z0 += *(const floatx4*)&red[((slot * 2 + 0) * 64 + lane) * 4];
      z1 += *(const floatx4*)&red[((slot * 2 + 1) * 64 + lane) * 4];
    }
    z0 += bias0;
    z1 += bias1;

    unsigned short* hW = layer ? h1r[t & 1] : h0r[t & 3];
    float2 f2s[4];

#pragma unroll
    for (int r = 0; r < 4; ++r) {
      float zi = z0[r], zg = z1[r];
      float zf = __shfl_xor(zi, 8);
      float zo = __shfl_xor(zg, 8);
      float hu_f = 0.f;
      unsigned short hu = 0;
      if (c16 < 8) {
        float ig = sigmf(zi), fg = sigmf(zf), gg = tanhfa(zg), og = sigmf(zo);
        float cn = fg * cst[r] + ig * gg;
        float hn = og * tanhfa(cn);
        bool m = t < lens4[r];
        float h2 = m ? hn : hst[r];
        float c2 = m ? cn : cst[r];
        hst[r] = h2;
        cst[r] = c2;
        hu = f2bf(h2);
        hu_f = h2;
        hstage[(wave * 16 + rowgrp * 4 + r) * 8 + c16] = hu;  // stage for block store
      }
      // pair adjacent cols for the rnnout float2 store (layer1 only)
      float hp = __shfl_xor(hu_f, 1);
      if (c16 < 8 && !(c16 & 1)) f2s[r] = make_float2(hu_f, hp);
    }

    // publish: wave0 stores the WG's whole 1KB block (coalesced, 2 insts/lane),
    // drains (2 stores -> ~1 RTT), then stores the epoch flag.
    __syncthreads();
    if (wave == 0) {
      const ull* hs = (const ull*)hstage;
      ull q0 = hs[2 * lane], q1 = hs[2 * lane + 1];
      char* dst = (char*)hW + (size_t)sub * 1024 + (size_t)lane * 16;
      AT_ST((ull*)dst, q0);
      AT_ST((ull*)(dst + 8), q1);
      asm volatile("s_waitcnt vmcnt(0)" ::: "memory");
      if (lane == 0) AT_ST(flagsL + sub, (unsigned)(t + 1));
    }

    // rnnout f32 stores AFTER the publish: off the drain path.
    if (layer && c16 < 8 && !(c16 & 1)) {
#pragma unroll
      for (int r = 0; r < 4; ++r) {
        int b = wave * 16 + rowgrp * 4 + r;
        *(float2*)&out[((size_t)b * 512 + (size_t)t) * 1024 + col] = f2s[r];
      }
    }
  }

  if (layer && c16 < 8) {
#pragma unroll
    for (int r = 0; r < 4; ++r) {
      int b = wave * 16 + rowgrp * 4 + r;
      out[(size_t)33554432 + (size_t)b * 1024 + col] = hst[r];
      out[(size_t)33554432 + 65536 + (size_t)b * 1024 + col] = cst[r];
    }
  }
}

extern "C" void kernel_launch(void* const* d_in, const int* in_sizes, int n_in,
                              void* d_out, int out_size, void* d_ws, size_t ws_size,
                              hipStream_t stream) {
  (void)in_sizes; (void)n_in; (void)out_size; (void)ws_size;
  const float* x  = (const float*)d_in[0];
  const int* lens = (const int*)d_in[1];
  const float* W0 = (const float*)d_in[2];
  const float* U0 = (const float*)d_in[3];
  const float* b0 = (const float*)d_in[4];
  const float* W1 = (const float*)d_in[5];
  const float* U1 = (const float*)d_in[6];
  const float* b1 = (const float*)d_in[7];

  (void)hipFuncSetAttribute((const void*)lstm2_persist,
                            hipFuncAttributeMaxDynamicSharedMemorySize, LDS_TOTAL);
  hipMemsetAsync(d_ws, 0, 16384, stream);  // flags0/flags1/fbar

  lstm2_persist<<<dim3(256), dim3(256), LDS_TOTAL, stream>>>(
      x, lens, W0, U0, b0, W1, U1, b1, (float*)d_out, (ull*)d_ws);
}